// Round 1
// baseline (718.667 us; speedup 1.0000x reference)
//
#include <hip/hip_runtime.h>
#include <math.h>

// Problem constants (match reference setup_inputs)
#define BB 4
#define LL 1024
#define DD 512
#define HH 8
#define DHH 64
#define EE 65536
#define NNODES 4096        // B*L
#define HD 512             // H*DH
#define TWO_D 1024

#define BM 64
#define BN 64
#define BK 16

// ---------------------------------------------------------------------------
// Shared GEMM tile core: C[m0:m0+64, n0:n0+64] += A[M,K] @ B
//   BT=false: B row-major [K][N] (ldb = row stride)
//   BT=true : B row-major [N][K] (ldb = row stride)  (i.e. C = A @ B^T)
// 256 threads, each computes a 4x4 micro-tile. kend must be a multiple of 16.
// ---------------------------------------------------------------------------
template <bool BT>
__device__ __forceinline__ void gemm_tile(const float* __restrict__ A, int lda,
                                          const float* __restrict__ Bm, int ldb,
                                          int m0, int n0, int kend,
                                          float (&acc)[4][4],
                                          float (&As)[BK][BM], float (&Bs)[BK][BN]) {
  const int tid = threadIdx.x;
  const int ar = tid >> 2, ak = (tid & 3) << 2;   // A-tile loader coords
  const int br = tid >> 4, bc = (tid & 15) << 2;  // B-tile loader coords (NN)
  const int ty = tid >> 4, tx = tid & 15;         // compute coords

  for (int k0 = 0; k0 < kend; k0 += BK) {
    float4 av = *(const float4*)(A + (size_t)(m0 + ar) * lda + (k0 + ak));
    As[ak + 0][ar] = av.x; As[ak + 1][ar] = av.y;
    As[ak + 2][ar] = av.z; As[ak + 3][ar] = av.w;
    if constexpr (BT) {
      float4 bv = *(const float4*)(Bm + (size_t)(n0 + ar) * ldb + (k0 + ak));
      Bs[ak + 0][ar] = bv.x; Bs[ak + 1][ar] = bv.y;
      Bs[ak + 2][ar] = bv.z; Bs[ak + 3][ar] = bv.w;
    } else {
      *(float4*)&Bs[br][bc] = *(const float4*)(Bm + (size_t)(k0 + br) * ldb + (n0 + bc));
    }
    __syncthreads();
#pragma unroll
    for (int kk = 0; kk < BK; ++kk) {
      float4 a4 = *(const float4*)&As[kk][ty << 2];
      float4 b4 = *(const float4*)&Bs[kk][tx << 2];
      float af[4] = {a4.x, a4.y, a4.z, a4.w};
      float bf[4] = {b4.x, b4.y, b4.z, b4.w};
#pragma unroll
      for (int i = 0; i < 4; ++i)
#pragma unroll
        for (int j = 0; j < 4; ++j)
          acc[i][j] = fmaf(af[i], bf[j], acc[i][j]);
    }
    __syncthreads();
  }
}

// ---------------------------------------------------------------------------
// Block reduction helpers (256 threads = 4 waves of 64)
// ---------------------------------------------------------------------------
__device__ __forceinline__ float block_sum(float v, float* red) {
#pragma unroll
  for (int o = 32; o > 0; o >>= 1) v += __shfl_down(v, o, 64);
  __syncthreads();
  if ((threadIdx.x & 63) == 0) red[threadIdx.x >> 6] = v;
  __syncthreads();
  return red[0] + red[1] + red[2] + red[3];
}

__device__ __forceinline__ float block_max(float v, float* red) {
#pragma unroll
  for (int o = 32; o > 0; o >>= 1) v = fmaxf(v, __shfl_down(v, o, 64));
  __syncthreads();
  if ((threadIdx.x & 63) == 0) red[threadIdx.x >> 6] = v;
  __syncthreads();
  return fmaxf(fmaxf(red[0], red[1]), fmaxf(red[2], red[3]));
}

// ---------------------------------------------------------------------------
// 1) QKV projection: out[b][h][l][dh] = (x @ W + bias)  (scatter to head layout)
//    grid (HD/BN=8, N/BM=64)
// ---------------------------------------------------------------------------
__global__ __launch_bounds__(256) void k_gemm_qkv(const float* __restrict__ x,
                                                  const float* __restrict__ W,
                                                  const float* __restrict__ bias,
                                                  float* __restrict__ outT) {
  __shared__ __align__(16) float As[BK][BM];
  __shared__ __align__(16) float Bs[BK][BN];
  const int m0 = blockIdx.y * BM, n0 = blockIdx.x * BN;
  float acc[4][4] = {};
  gemm_tile<false>(x, DD, W, HD, m0, n0, DD, acc, As, Bs);
  const int ty = threadIdx.x >> 4, tx = threadIdx.x & 15;
  const int h = n0 >> 6;                 // BN==DH so each tile is one head
  const int c0 = n0 + (tx << 2);
#pragma unroll
  for (int i = 0; i < 4; ++i) {
    int row = m0 + (ty << 2) + i;        // row = b*L + l
    int b = row >> 10, l = row & 1023;
    float4 ov;
    ov.x = acc[i][0] + bias[c0 + 0];
    ov.y = acc[i][1] + bias[c0 + 1];
    ov.z = acc[i][2] + bias[c0 + 2];
    ov.w = acc[i][3] + bias[c0 + 3];
    *(float4*)&outT[((size_t)((b * HH + h) * LL + l)) * DHH + (c0 & 63)] = ov;
  }
}

// ---------------------------------------------------------------------------
// 2) g = x + x @ Wmp + bmp      (message-passing hoisted out of the gather)
// ---------------------------------------------------------------------------
__global__ __launch_bounds__(256) void k_gemm_g(const float* __restrict__ x,
                                                const float* __restrict__ Wmp,
                                                const float* __restrict__ bmp,
                                                float* __restrict__ g) {
  __shared__ __align__(16) float As[BK][BM];
  __shared__ __align__(16) float Bs[BK][BN];
  const int m0 = blockIdx.y * BM, n0 = blockIdx.x * BN;
  float acc[4][4] = {};
  gemm_tile<false>(x, DD, Wmp, DD, m0, n0, DD, acc, As, Bs);
  const int ty = threadIdx.x >> 4, tx = threadIdx.x & 15;
  const int c0 = n0 + (tx << 2);
  float4 bv = *(const float4*)&bmp[c0];
#pragma unroll
  for (int i = 0; i < 4; ++i) {
    int row = m0 + (ty << 2) + i;
    float4 xv = *(const float4*)&x[(size_t)row * DD + c0];
    float4 ov;
    ov.x = acc[i][0] + bv.x + xv.x;
    ov.y = acc[i][1] + bv.y + xv.y;
    ov.z = acc[i][2] + bv.z + xv.z;
    ov.w = acc[i][3] + bv.w + xv.w;
    *(float4*)&g[(size_t)row * DD + c0] = ov;
  }
}

// ---------------------------------------------------------------------------
// 3) Plain GEMM + bias: C[M,Nn] = A[M,K] @ W[K,Nn] + bias
// ---------------------------------------------------------------------------
__global__ __launch_bounds__(256) void k_gemm_bias(const float* __restrict__ A,
                                                   const float* __restrict__ W,
                                                   const float* __restrict__ bias,
                                                   float* __restrict__ C,
                                                   int Nn, int K) {
  __shared__ __align__(16) float As[BK][BM];
  __shared__ __align__(16) float Bs[BK][BN];
  const int m0 = blockIdx.y * BM, n0 = blockIdx.x * BN;
  float acc[4][4] = {};
  gemm_tile<false>(A, K, W, Nn, m0, n0, K, acc, As, Bs);
  const int ty = threadIdx.x >> 4, tx = threadIdx.x & 15;
  const int c0 = n0 + (tx << 2);
  float4 bv = *(const float4*)&bias[c0];
#pragma unroll
  for (int i = 0; i < 4; ++i) {
    int row = m0 + (ty << 2) + i;
    float4 ov;
    ov.x = acc[i][0] + bv.x;
    ov.y = acc[i][1] + bv.y;
    ov.z = acc[i][2] + bv.z;
    ov.w = acc[i][3] + bv.w;
    *(float4*)&C[(size_t)row * Nn + c0] = ov;
  }
}

// ---------------------------------------------------------------------------
// 4) Segment mean over sorted indicator: hp[s] = mean_{e: ind[e]==s} g[idx[e]]
//    grid 4096 blocks x 128 threads (float4 per thread over D=512)
// ---------------------------------------------------------------------------
__global__ __launch_bounds__(128) void k_segmean(const float* __restrict__ g,
                                                 const int* __restrict__ idx,
                                                 const int* __restrict__ ind,
                                                 float* __restrict__ hp) {
  __shared__ int sh[2];
  const int s = blockIdx.x;
  if (threadIdx.x == 0) {
    int lo = 0, hi = EE;
    while (lo < hi) { int mid = (lo + hi) >> 1; if (ind[mid] < s) lo = mid + 1; else hi = mid; }
    sh[0] = lo;
    int lo2 = lo, hi2 = EE;
    while (lo2 < hi2) { int mid = (lo2 + hi2) >> 1; if (ind[mid] <= s) lo2 = mid + 1; else hi2 = mid; }
    sh[1] = lo2;
  }
  __syncthreads();
  const int lo = sh[0], hi = sh[1];
  const int d0 = threadIdx.x << 2;
  float ax = 0.f, ay = 0.f, az = 0.f, aw = 0.f;
  for (int e = lo; e < hi; ++e) {
    int r = idx[e];
    float4 v = *(const float4*)&g[(size_t)r * DD + d0];
    ax += v.x; ay += v.y; az += v.z; aw += v.w;
  }
  float invc = (hi > lo) ? 1.0f / (float)(hi - lo) : 0.0f;
  float4 o = {ax * invc, ay * invc, az * invc, aw * invc};
  *(float4*)&hp[(size_t)s * DD + d0] = o;
}

// ---------------------------------------------------------------------------
// 5) BatchNorm column stats over concat([x, hp]) : 1024 features x 4096 rows
// ---------------------------------------------------------------------------
__global__ __launch_bounds__(256) void k_stats(const float* __restrict__ x,
                                               const float* __restrict__ hp,
                                               float* __restrict__ mu,
                                               float* __restrict__ inv) {
  __shared__ float red[4];
  const int f = blockIdx.x;
  const float* src = (f < DD) ? (x + f) : (hp + (f - DD));
  float s = 0.f, ss = 0.f;
  for (int n = threadIdx.x; n < NNODES; n += 256) {
    float v = src[(size_t)n * DD];
    s += v;
    ss = fmaf(v, v, ss);
  }
  s = block_sum(s, red);
  ss = block_sum(ss, red);
  if (threadIdx.x == 0) {
    float m = s * (1.0f / NNODES);
    float var = ss * (1.0f / NNODES) - m * m;
    mu[f] = m;
    inv[f] = rsqrtf(var + 1e-5f);
  }
}

// ---------------------------------------------------------------------------
// 6) normed[n][f] = (concat(x,hp)[n][f] - mu[f]) * inv[f] * gamma[f] + beta[f]
//    grid 4096 x 256, one float4 per thread
// ---------------------------------------------------------------------------
__global__ __launch_bounds__(256) void k_norm(const float* __restrict__ x,
                                              const float* __restrict__ hp,
                                              const float* __restrict__ mu,
                                              const float* __restrict__ inv,
                                              const float* __restrict__ gamma,
                                              const float* __restrict__ beta,
                                              float* __restrict__ normed) {
  const int gid = blockIdx.x * 256 + threadIdx.x;
  const int n = gid >> 8;          // 256 float4 per row of 1024
  const int f = (gid & 255) << 2;
  float4 v;
  if (f < DD) v = *(const float4*)&x[(size_t)n * DD + f];
  else        v = *(const float4*)&hp[(size_t)n * DD + (f - DD)];
  float4 o;
  o.x = (v.x - mu[f + 0]) * inv[f + 0] * gamma[f + 0] + beta[f + 0];
  o.y = (v.y - mu[f + 1]) * inv[f + 1] * gamma[f + 1] + beta[f + 1];
  o.z = (v.z - mu[f + 2]) * inv[f + 2] * gamma[f + 2] + beta[f + 2];
  o.w = (v.w - mu[f + 3]) * inv[f + 3] * gamma[f + 3] + beta[f + 3];
  *(float4*)&normed[(size_t)n * TWO_D + f] = o;
}

// ---------------------------------------------------------------------------
// 7) K_struct[b] = ex_b @ ex_b^T / sqrt(D)    grid (16,16,4)
// ---------------------------------------------------------------------------
__global__ __launch_bounds__(256) void k_kstruct(const float* __restrict__ ex,
                                                 float* __restrict__ Ks) {
  __shared__ __align__(16) float As[BK][BM];
  __shared__ __align__(16) float Bs[BK][BN];
  const int z = blockIdx.z;
  const int m0 = blockIdx.y * BM, n0 = blockIdx.x * BN;
  const float* Az = ex + (size_t)z * LL * DD;
  float acc[4][4] = {};
  gemm_tile<true>(Az, DD, Az, DD, m0, n0, DD, acc, As, Bs);
  const int ty = threadIdx.x >> 4, tx = threadIdx.x & 15;
  const float sc = 0.04419417382415922f;  // 1/sqrt(512)
  float* Cz = Ks + (size_t)z * LL * LL;
#pragma unroll
  for (int i = 0; i < 4; ++i) {
    int row = m0 + (ty << 2) + i;
    float4 ov;
    ov.x = acc[i][0] * sc; ov.y = acc[i][1] * sc;
    ov.z = acc[i][2] * sc; ov.w = acc[i][3] * sc;
    *(float4*)&Cz[(size_t)row * LL + n0 + (tx << 2)] = ov;
  }
}

// ---------------------------------------------------------------------------
// 8) scores = q@k^T * 0.125 + ss*Ks + Bg  (raw, pre-softmax; masked tiles skipped)
//    grid (16,16,32)  z = b*H + h
// ---------------------------------------------------------------------------
__global__ __launch_bounds__(256) void k_scores(const float* __restrict__ qT,
                                                const float* __restrict__ kT,
                                                const float* __restrict__ Ks,
                                                const float* __restrict__ Bg,
                                                const float* __restrict__ ssp,
                                                float* __restrict__ attn) {
  const int m0 = blockIdx.y * BM, n0 = blockIdx.x * BN;
  if (n0 > m0 + (BM - 1)) return;  // entirely above the causal diagonal
  __shared__ __align__(16) float As[BK][BM];
  __shared__ __align__(16) float Bs[BK][BN];
  const int z = blockIdx.z;
  const int b = z >> 3;
  const float* A = qT + (size_t)z * LL * DHH;
  const float* Bm = kT + (size_t)z * LL * DHH;
  float acc[4][4] = {};
  gemm_tile<true>(A, DHH, Bm, DHH, m0, n0, DHH, acc, As, Bs);
  const int ty = threadIdx.x >> 4, tx = threadIdx.x & 15;
  const float ss = ssp[0];
  const int c0 = n0 + (tx << 2);
  const float* Ksb = Ks + (size_t)b * LL * LL;
  const float* Bgb = Bg + (size_t)b * LL * LL;
  float* Cz = attn + (size_t)z * LL * LL;
#pragma unroll
  for (int i = 0; i < 4; ++i) {
    int row = m0 + (ty << 2) + i;
    float4 kv = *(const float4*)&Ksb[(size_t)row * LL + c0];
    float4 gv = *(const float4*)&Bgb[(size_t)row * LL + c0];
    float4 ov;
    ov.x = fmaf(acc[i][0], 0.125f, fmaf(ss, kv.x, gv.x));
    ov.y = fmaf(acc[i][1], 0.125f, fmaf(ss, kv.y, gv.y));
    ov.z = fmaf(acc[i][2], 0.125f, fmaf(ss, kv.z, gv.z));
    ov.w = fmaf(acc[i][3], 0.125f, fmaf(ss, kv.w, gv.w));
    *(float4*)&Cz[(size_t)row * LL + c0] = ov;
  }
}

// ---------------------------------------------------------------------------
// 9) Causal row softmax in-place on attn; zeros written above the diagonal.
//    grid (1024, 32), 256 threads
// ---------------------------------------------------------------------------
__global__ __launch_bounds__(256) void k_softmax(float* __restrict__ attn) {
  __shared__ float buf[LL];
  __shared__ float red[4];
  const int i = blockIdx.x;
  const int bh = blockIdx.y;
  float* row = attn + ((size_t)bh * LL + i) * LL;
  const int jmax = i + 1;
  float mx = -INFINITY;
  for (int j = threadIdx.x; j < jmax; j += 256) {
    float v = row[j];
    buf[j] = v;
    mx = fmaxf(mx, v);
  }
  mx = block_max(mx, red);
  float sm = 0.f;
  for (int j = threadIdx.x; j < jmax; j += 256) {
    float e = expf(buf[j] - mx);
    buf[j] = e;
    sm += e;
  }
  sm = block_sum(sm, red);
  const float is = 1.0f / sm;
  for (int j = threadIdx.x; j < LL; j += 256)
    row[j] = (j < jmax) ? buf[j] * is : 0.0f;
}

// ---------------------------------------------------------------------------
// 10) PV: o[b*L+l][h*64+dh] = attn[b,h,l,:] @ v[b,h,:,dh]; K clipped at diagonal
//     grid (1,16,32)
// ---------------------------------------------------------------------------
__global__ __launch_bounds__(256) void k_pv(const float* __restrict__ attn,
                                            const float* __restrict__ vT,
                                            float* __restrict__ o) {
  __shared__ __align__(16) float As[BK][BM];
  __shared__ __align__(16) float Bs[BK][BN];
  const int z = blockIdx.z;
  const int b = z >> 3, h = z & 7;
  const int m0 = blockIdx.y * BM, n0 = 0;
  const int kend = m0 + BM;  // attn[i][j]==0 for j>i; tile max i = m0+63
  float acc[4][4] = {};
  gemm_tile<false>(attn + (size_t)z * LL * LL, LL, vT + (size_t)z * LL * DHH, DHH,
                   m0, n0, kend, acc, As, Bs);
  const int ty = threadIdx.x >> 4, tx = threadIdx.x & 15;
  const int c0 = n0 + (tx << 2);
#pragma unroll
  for (int i = 0; i < 4; ++i) {
    int row = m0 + (ty << 2) + i;  // l
    float4 ov = {acc[i][0], acc[i][1], acc[i][2], acc[i][3]};
    *(float4*)&o[((size_t)(b * LL + row)) * HD + h * DHH + c0] = ov;
  }
}

// ---------------------------------------------------------------------------
extern "C" void kernel_launch(void* const* d_in, const int* in_sizes, int n_in,
                              void* d_out, int out_size, void* d_ws, size_t ws_size,
                              hipStream_t stream) {
  const float* x     = (const float*)d_in[0];
  // d_in[1] = lattice (unused), d_in[5] = attn_mask (deterministic causal; computed analytically)
  const float* Bg    = (const float*)d_in[2];
  const int*   sidx  = (const int*)d_in[3];
  const int*   sind  = (const int*)d_in[4];
  const float* Wq    = (const float*)d_in[6];
  const float* bq    = (const float*)d_in[7];
  const float* Wk    = (const float*)d_in[8];
  const float* bk    = (const float*)d_in[9];
  const float* Wv    = (const float*)d_in[10];
  const float* bv    = (const float*)d_in[11];
  const float* Wo    = (const float*)d_in[12];
  const float* bo    = (const float*)d_in[13];
  const float* Wmp   = (const float*)d_in[14];
  const float* bmp   = (const float*)d_in[15];
  const float* gamma = (const float*)d_in[16];
  const float* beta  = (const float*)d_in[17];
  const float* Wex   = (const float*)d_in[18];
  const float* bex   = (const float*)d_in[19];
  const float* ssp   = (const float*)d_in[20];

  float* ws = (float*)d_ws;
  // Workspace layout (floats); total 23,070,720 floats = 92.3 MB
  float* qT     = ws;                   // [B,H,L,DH]  2097152
  float* kT     = ws + 2097152;         // 2097152
  float* vT     = ws + 4194304;         // 2097152
  float* g      = ws + 6291456;         // [N,D]       2097152
  float* hp     = ws + 8388608;         // [N,D]       2097152
  float* ex     = ws + 10485760;        // [N,D]       2097152
  float* o      = ws + 12582912;        // [N,HD]      2097152
  float* normed = ws + 14680064;        // [N,2D]      4194304
  float* Ks     = ws + 18874368;        // [B,L,L]     4194304
  float* muv    = ws + 23068672;        // 1024
  float* invv   = ws + 23069696;        // 1024

  float* outp = (float*)d_out;                    // [B,L,HD] 2097152 floats
  float* attn = outp + (size_t)BB * LL * HD;      // [B,H,L,L] 33554432 floats

  dim3 thr(256);

  // QKV projections
  k_gemm_qkv<<<dim3(HD / BN, NNODES / BM), thr, 0, stream>>>(x, Wq, bq, qT);
  k_gemm_qkv<<<dim3(HD / BN, NNODES / BM), thr, 0, stream>>>(x, Wk, bk, kT);
  k_gemm_qkv<<<dim3(HD / BN, NNODES / BM), thr, 0, stream>>>(x, Wv, bv, vT);

  // GNN extractor
  k_gemm_g<<<dim3(DD / BN, NNODES / BM), thr, 0, stream>>>(x, Wmp, bmp, g);
  k_segmean<<<dim3(NNODES), dim3(128), 0, stream>>>(g, sidx, sind, hp);
  k_stats<<<dim3(TWO_D), thr, 0, stream>>>(x, hp, muv, invv);
  k_norm<<<dim3((NNODES * TWO_D / 4) / 256), thr, 0, stream>>>(x, hp, muv, invv, gamma, beta, normed);
  k_gemm_bias<<<dim3(DD / BN, NNODES / BM), thr, 0, stream>>>(normed, Wex, bex, ex, DD, TWO_D);

  // Structural bias K = ex @ ex^T / sqrt(D)
  k_kstruct<<<dim3(LL / BN, LL / BM, BB), thr, 0, stream>>>(ex, Ks);

  // Attention
  k_scores<<<dim3(LL / BN, LL / BM, BB * HH), thr, 0, stream>>>(qT, kT, Ks, Bg, ssp, attn);
  k_softmax<<<dim3(LL, BB * HH), thr, 0, stream>>>(attn);
  k_pv<<<dim3(1, LL / BM, BB * HH), thr, 0, stream>>>(attn, vT, o);

  // Output projection
  k_gemm_bias<<<dim3(HD / BN, NNODES / BM), thr, 0, stream>>>(o, Wo, bo, outp, HD, DD);
}

// Round 4
// 408.689 us; speedup vs baseline: 1.7585x; 1.7585x over previous
//
#include <hip/hip_runtime.h>
#include <math.h>

// Problem constants
#define BB 4
#define LL 1024
#define DD 512
#define HH 8
#define DHH 64
#define EE 65536
#define NNODES 4096
#define HD 512
#define TWO_D 1024

typedef short bf16x8 __attribute__((ext_vector_type(8)));
typedef short short4v __attribute__((ext_vector_type(4)));
typedef float f32x4 __attribute__((ext_vector_type(4)));
typedef unsigned int u32;
#define GL_AS __attribute__((address_space(1)))
#define LDS_AS __attribute__((address_space(3)))

__device__ __forceinline__ short f2bf(float f) {   // RNE fp32->bf16
  u32 u = __builtin_bit_cast(u32, f);
  u = (u + 0x7fffu + ((u >> 16) & 1u)) >> 16;
  return (short)u;
}
__device__ __forceinline__ float b2f(short s) {
  u32 u = ((u32)(unsigned short)s) << 16;
  return __builtin_bit_cast(float, u);
}
__device__ __forceinline__ void gload_lds16(const short* g, short* l) {
  __builtin_amdgcn_global_load_lds((GL_AS const u32*)g, (LDS_AS u32*)l, 16, 0, 0);
}

// ---- stage ROWS x 32 bf16 tile (global row stride lda elems) -> LDS [ROWS][32]
template <int ROWS>
__device__ __forceinline__ void stage32(const short* g, int lda, short* lds, int tid) {
  const int w = tid >> 6, l = tid & 63;
#pragma unroll
  for (int rep = 0; rep < ROWS / 64; ++rep) {
    const int rbase = rep * 64 + w * 16;
    gload_lds16(g + (size_t)(rbase + (l >> 2)) * lda + (l & 3) * 8, lds + rbase * 32);
  }
}
// ---- stage 128 x 64 bf16 tile -> LDS [128][64]
__device__ __forceinline__ void stage64x128(const short* g, int lda, short* lds, int tid) {
  const int w = tid >> 6, l = tid & 63;
#pragma unroll
  for (int rep = 0; rep < 4; ++rep) {
    const int rbase = rep * 32 + w * 8;
    gload_lds16(g + (size_t)(rbase + (l >> 3)) * lda + (l & 7) * 8, lds + rbase * 64);
  }
}

// ---- one K=32 MFMA step from LDS tiles (BT layout both sides)
template <int MREP, int NREP>
__device__ __forceinline__ void mfma_step(const short* As, const short* Bs, int lds_ld, int kofs,
                                          f32x4 (&acc)[MREP][NREP], int wr, int wc, int l) {
  bf16x8 a[MREP], b[NREP];
#pragma unroll
  for (int mi = 0; mi < MREP; ++mi) {
    const int row = wr * (MREP * 16) + mi * 16 + (l & 15);
    a[mi] = *(const bf16x8*)(As + row * lds_ld + kofs + ((l >> 4) << 3));
  }
#pragma unroll
  for (int ni = 0; ni < NREP; ++ni) {
    const int row = wc * (NREP * 16) + ni * 16 + (l & 15);
    b[ni] = *(const bf16x8*)(Bs + row * lds_ld + kofs + ((l >> 4) << 3));
  }
#pragma unroll
  for (int mi = 0; mi < MREP; ++mi)
#pragma unroll
    for (int ni = 0; ni < NREP; ++ni)
      acc[mi][ni] = __builtin_amdgcn_mfma_f32_16x16x32_bf16(a[mi], b[ni], acc[mi][ni], 0, 0, 0);
}

// ===========================================================================
// casts
// ===========================================================================
__global__ __launch_bounds__(256) void k_cast_x(const float* __restrict__ x, short* __restrict__ xb) {
  const int i = (blockIdx.x * 256 + threadIdx.x) * 8;
  float4 f0 = *(const float4*)(x + i), f1 = *(const float4*)(x + i + 4);
  bf16x8 s;
  s[0] = f2bf(f0.x); s[1] = f2bf(f0.y); s[2] = f2bf(f0.z); s[3] = f2bf(f0.w);
  s[4] = f2bf(f1.x); s[5] = f2bf(f1.y); s[6] = f2bf(f1.z); s[7] = f2bf(f1.w);
  *(bf16x8*)(xb + i) = s;
}

// W fp32 [K][N] -> out bf16 [N][K]; grid (N/32, K/32), block (32,8)
__global__ __launch_bounds__(256) void k_tcast(const float* __restrict__ W, short* __restrict__ out,
                                               int K, int N) {
  __shared__ float t[32][33];
  const int k0 = blockIdx.y * 32, n0 = blockIdx.x * 32;
  const int tx = threadIdx.x, ty = threadIdx.y;
#pragma unroll
  for (int i = 0; i < 4; ++i)
    t[ty + 8 * i][tx] = W[(size_t)(k0 + ty + 8 * i) * N + n0 + tx];
  __syncthreads();
#pragma unroll
  for (int i = 0; i < 4; ++i)
    out[(size_t)(n0 + ty + 8 * i) * K + k0 + tx] = f2bf(t[tx][ty + 8 * i]);
}

__global__ __launch_bounds__(256) void k_pack_bias(const float* bq, const float* bk,
                                                   const float* bv, const float* bmp,
                                                   float* __restrict__ bcat) {
  const int i = blockIdx.x * 256 + threadIdx.x;
  const float* src = (i < 512) ? bq : (i < 1024) ? bk : (i < 1536) ? bv : bmp;
  bcat[i] = src[i & 511];
}

// ===========================================================================
// fused QKV + message-passing GEMM: [4096x512] @ [512x2048] (BT weights)
// grid (16, 32), 256 thr, 128x128 tile
// ===========================================================================
__global__ __launch_bounds__(256) void k_gemm_qkvg(const short* __restrict__ A,
                                                   const short* __restrict__ Bw,
                                                   const float* __restrict__ bcat,
                                                   const float* __restrict__ x,
                                                   short* __restrict__ qT, short* __restrict__ kT,
                                                   short* __restrict__ vT, short* __restrict__ g_bf) {
  __shared__ __align__(16) short As[128 * 32];
  __shared__ __align__(16) short Bs[128 * 32];
  const int tid = threadIdx.x, l = tid & 63, w = tid >> 6, wr = w >> 1, wc = w & 1;
  const int m0 = blockIdx.y * 128, n0 = blockIdx.x * 128;
  f32x4 acc[4][4] = {};
  for (int k0 = 0; k0 < 512; k0 += 32) {
    stage32<128>(A + (size_t)m0 * 512 + k0, 512, As, tid);
    stage32<128>(Bw + (size_t)n0 * 512 + k0, 512, Bs, tid);
    __syncthreads();
    mfma_step<4, 4>(As, Bs, 32, 0, acc, wr, wc, l);
    __syncthreads();
  }
  const int lr = l >> 4, lc = l & 15;
#pragma unroll
  for (int mi = 0; mi < 4; ++mi)
#pragma unroll
    for (int ni = 0; ni < 4; ++ni) {
      const int col = n0 + wc * 64 + ni * 16 + lc;
      const int which = col >> 9;
#pragma unroll
      for (int r = 0; r < 4; ++r) {
        const int row = m0 + wr * 64 + mi * 16 + lr * 4 + r;
        float v = acc[mi][ni][r] + bcat[col];
        if (which < 3) {
          const int hh = (col >> 6) & 7, dh = col & 63;
          const int bb = row >> 10, ll2 = row & 1023;
          short* dst = (which == 0) ? qT : (which == 1) ? kT : vT;
          dst[((size_t)((bb * 8 + hh) * 1024 + ll2)) * 64 + dh] = f2bf(v);
        } else {
          const int c = col & 511;
          g_bf[(size_t)row * 512 + c] = f2bf(v + x[(size_t)row * 512 + c]);
        }
      }
    }
}

// ===========================================================================
// generic BT GEMM 64x128 tile (MREP=2): ex
// ===========================================================================
__global__ __launch_bounds__(256) void k_gemm_ex(const short* __restrict__ A,
                                                 const short* __restrict__ Bw,
                                                 const float* __restrict__ bias,
                                                 short* __restrict__ C) {
  __shared__ __align__(16) short As[64 * 32];
  __shared__ __align__(16) short Bs[128 * 32];
  const int tid = threadIdx.x, l = tid & 63, w = tid >> 6, wr = w >> 1, wc = w & 1;
  const int m0 = blockIdx.y * 64, n0 = blockIdx.x * 128;
  f32x4 acc[2][4] = {};
  for (int k0 = 0; k0 < 1024; k0 += 32) {
    stage32<64>(A + (size_t)m0 * 1024 + k0, 1024, As, tid);
    stage32<128>(Bw + (size_t)n0 * 1024 + k0, 1024, Bs, tid);
    __syncthreads();
    mfma_step<2, 4>(As, Bs, 32, 0, acc, wr, wc, l);
    __syncthreads();
  }
  const int lr = l >> 4, lc = l & 15;
#pragma unroll
  for (int mi = 0; mi < 2; ++mi)
#pragma unroll
    for (int ni = 0; ni < 4; ++ni) {
      const int col = n0 + wc * 64 + ni * 16 + lc;
      const float bv = bias[col];
#pragma unroll
      for (int r = 0; r < 4; ++r) {
        const int row = m0 + wr * 32 + mi * 16 + lr * 4 + r;
        C[(size_t)row * 512 + col] = f2bf(acc[mi][ni][r] + bv);
      }
    }
}

__global__ __launch_bounds__(256) void k_gemm_oproj(const short* __restrict__ A,
                                                    const short* __restrict__ Bw,
                                                    const float* __restrict__ bias,
                                                    float* __restrict__ C) {
  __shared__ __align__(16) short As[64 * 32];
  __shared__ __align__(16) short Bs[128 * 32];
  const int tid = threadIdx.x, l = tid & 63, w = tid >> 6, wr = w >> 1, wc = w & 1;
  const int m0 = blockIdx.y * 64, n0 = blockIdx.x * 128;
  f32x4 acc[2][4] = {};
  for (int k0 = 0; k0 < 512; k0 += 32) {
    stage32<64>(A + (size_t)m0 * 512 + k0, 512, As, tid);
    stage32<128>(Bw + (size_t)n0 * 512 + k0, 512, Bs, tid);
    __syncthreads();
    mfma_step<2, 4>(As, Bs, 32, 0, acc, wr, wc, l);
    __syncthreads();
  }
  const int lr = l >> 4, lc = l & 15;
#pragma unroll
  for (int mi = 0; mi < 2; ++mi)
#pragma unroll
    for (int ni = 0; ni < 4; ++ni) {
      const int col = n0 + wc * 64 + ni * 16 + lc;
      const float bv = bias[col];
#pragma unroll
      for (int r = 0; r < 4; ++r) {
        const int row = m0 + wr * 32 + mi * 16 + lr * 4 + r;
        C[(size_t)row * 512 + col] = acc[mi][ni][r] + bv;
      }
    }
}

// ===========================================================================
// K_struct combined bias: Ksc = ss * (ex@ex^T)/sqrt(512) + Bg   (causal tiles)
// grid (8, 8, 4)
// ===========================================================================
__global__ __launch_bounds__(256) void k_kstruct(const short* __restrict__ ex,
                                                 const float* __restrict__ Bg,
                                                 const float* __restrict__ ssp,
                                                 float* __restrict__ Ksc) {
  const int mt = blockIdx.y, nt = blockIdx.x, b = blockIdx.z;
  if (nt > mt) return;
  __shared__ __align__(16) short As[128 * 32];
  __shared__ __align__(16) short Bs[128 * 32];
  const int tid = threadIdx.x, l = tid & 63, w = tid >> 6, wr = w >> 1, wc = w & 1;
  const int m0 = mt * 128, n0 = nt * 128;
  const short* Az = ex + (size_t)b * 1024 * 512;
  f32x4 acc[4][4] = {};
  for (int k0 = 0; k0 < 512; k0 += 32) {
    stage32<128>(Az + (size_t)m0 * 512 + k0, 512, As, tid);
    stage32<128>(Az + (size_t)n0 * 512 + k0, 512, Bs, tid);
    __syncthreads();
    mfma_step<4, 4>(As, Bs, 32, 0, acc, wr, wc, l);
    __syncthreads();
  }
  const float sc = ssp[0] * 0.04419417382415922f;  // ss / sqrt(512)
  const float* Bgb = Bg + (size_t)b * 1024 * 1024;
  float* Kb = Ksc + (size_t)b * 1024 * 1024;
  const int lr = l >> 4, lc = l & 15;
#pragma unroll
  for (int mi = 0; mi < 4; ++mi)
#pragma unroll
    for (int ni = 0; ni < 4; ++ni) {
      const int col = n0 + wc * 64 + ni * 16 + lc;
#pragma unroll
      for (int r = 0; r < 4; ++r) {
        const int row = m0 + wr * 64 + mi * 16 + lr * 4 + r;
        Kb[(size_t)row * 1024 + col] = fmaf(acc[mi][ni][r], sc, Bgb[(size_t)row * 1024 + col]);
      }
    }
}

// ===========================================================================
// scores: raw = q@k^T * 0.125 + Ksc   (h looped inside so Ksc read once)
// grid (8, 8, 4)
// ===========================================================================
__global__ __launch_bounds__(256) void k_scores(const short* __restrict__ qT,
                                                const short* __restrict__ kT,
                                                const float* __restrict__ Ksc,
                                                float* __restrict__ attn) {
  const int mt = blockIdx.y, nt = blockIdx.x, b = blockIdx.z;
  if (nt > mt) return;
  __shared__ __align__(16) short Qs[128 * 64];
  __shared__ __align__(16) short Ks_[128 * 64];
  const int tid = threadIdx.x, l = tid & 63, w = tid >> 6, wr = w >> 1, wc = w & 1;
  const int m0 = mt * 128, n0 = nt * 128;
  const int lr = l >> 4, lc = l & 15;
  const float* Kb = Ksc + (size_t)b * 1024 * 1024;
  for (int h = 0; h < 8; ++h) {
    const int z = b * 8 + h;
    stage64x128(qT + (size_t)z * 1024 * 64 + (size_t)m0 * 64, 64, Qs, tid);
    stage64x128(kT + (size_t)z * 1024 * 64 + (size_t)n0 * 64, 64, Ks_, tid);
    __syncthreads();
    f32x4 acc[4][4] = {};
    mfma_step<4, 4>(Qs, Ks_, 64, 0, acc, wr, wc, l);
    mfma_step<4, 4>(Qs, Ks_, 64, 32, acc, wr, wc, l);
    float* Az = attn + (size_t)z * 1024 * 1024;
#pragma unroll
    for (int mi = 0; mi < 4; ++mi)
#pragma unroll
      for (int ni = 0; ni < 4; ++ni) {
        const int col = n0 + wc * 64 + ni * 16 + lc;
#pragma unroll
        for (int r = 0; r < 4; ++r) {
          const int row = m0 + wr * 64 + mi * 16 + lr * 4 + r;
          Az[(size_t)row * 1024 + col] =
              fmaf(acc[mi][ni][r], 0.125f, Kb[(size_t)row * 1024 + col]);
        }
      }
    __syncthreads();
  }
}

// ===========================================================================
// softmax (fp32 exact, causal), grid (1024, 32)
// ===========================================================================
__device__ __forceinline__ float block_sum(float v, float* red) {
#pragma unroll
  for (int o = 32; o > 0; o >>= 1) v += __shfl_down(v, o, 64);
  __syncthreads();
  if ((threadIdx.x & 63) == 0) red[threadIdx.x >> 6] = v;
  __syncthreads();
  return red[0] + red[1] + red[2] + red[3];
}
__device__ __forceinline__ float block_max(float v, float* red) {
#pragma unroll
  for (int o = 32; o > 0; o >>= 1) v = fmaxf(v, __shfl_down(v, o, 64));
  __syncthreads();
  if ((threadIdx.x & 63) == 0) red[threadIdx.x >> 6] = v;
  __syncthreads();
  return fmaxf(fmaxf(red[0], red[1]), fmaxf(red[2], red[3]));
}

__global__ __launch_bounds__(256) void k_softmax(float* __restrict__ attn) {
  __shared__ float buf[LL];
  __shared__ float red[4];
  const int i = blockIdx.x;
  float* row = attn + ((size_t)blockIdx.y * LL + i) * LL;
  const int jmax = i + 1;
  float mx = -INFINITY;
  for (int j = threadIdx.x; j < jmax; j += 256) {
    float v = row[j];
    buf[j] = v;
    mx = fmaxf(mx, v);
  }
  mx = block_max(mx, red);
  float sm = 0.f;
  for (int j = threadIdx.x; j < jmax; j += 256) {
    float e = expf(buf[j] - mx);
    buf[j] = e;
    sm += e;
  }
  sm = block_sum(sm, red);
  const float is = 1.0f / sm;
  for (int j = threadIdx.x; j < LL; j += 256)
    row[j] = (j < jmax) ? buf[j] * is : 0.0f;
}

// ===========================================================================
// PV: o = attn @ V  (bf16 MFMA; P converted fp32->bf16 in staging)
// grid (8, 32): x = mtile (128 rows), y = z
// ===========================================================================
__global__ __launch_bounds__(256) void k_pv(const float* __restrict__ attn,
                                            const short* __restrict__ vT,
                                            short* __restrict__ o_bf) {
  __shared__ __align__(16) short Pls[128 * 32];
  __shared__ __align__(16) short Vls[64 * 32];  // [dh][j]
  const int tid = threadIdx.x, l = tid & 63, w = tid >> 6;
  const int z = blockIdx.y, b = z >> 3, h = z & 7;
  const int m0 = blockIdx.x * 128;
  const float* Az = attn + (size_t)z * 1024 * 1024;
  const short* Vz = vT + (size_t)z * 1024 * 64;
  const int kend = m0 + 128;
  f32x4 acc[2][4] = {};
  const int pr = tid >> 1, jh = (tid & 1) * 16;   // P staging coords
  const int vj = tid >> 3, vd0 = (tid & 7) * 8;   // V staging coords
  for (int k0 = 0; k0 < kend; k0 += 32) {
    float tmpf[16];
    const float* src = Az + (size_t)(m0 + pr) * 1024 + k0 + jh;
#pragma unroll
    for (int c = 0; c < 4; ++c) *(float4*)(tmpf + c * 4) = *(const float4*)(src + c * 4);
    bf16x8 vv = *(const bf16x8*)(Vz + (size_t)(k0 + vj) * 64 + vd0);
    __syncthreads();
    bf16x8 s0, s1;
#pragma unroll
    for (int i = 0; i < 8; ++i) { s0[i] = f2bf(tmpf[i]); s1[i] = f2bf(tmpf[8 + i]); }
    *(bf16x8*)(Pls + pr * 32 + jh) = s0;
    *(bf16x8*)(Pls + pr * 32 + jh + 8) = s1;
#pragma unroll
    for (int i = 0; i < 8; ++i) Vls[(vd0 + i) * 32 + vj] = vv[i];
    __syncthreads();
    mfma_step<2, 4>(Pls, Vls, 32, 0, acc, w, 0, l);
  }
  const int lr = l >> 4, lc = l & 15;
#pragma unroll
  for (int mi = 0; mi < 2; ++mi)
#pragma unroll
    for (int ni = 0; ni < 4; ++ni)
#pragma unroll
      for (int r = 0; r < 4; ++r) {
        const int row = m0 + w * 32 + mi * 16 + lr * 4 + r;
        o_bf[((size_t)(b * 1024 + row)) * 512 + h * 64 + ni * 16 + lc] = f2bf(acc[mi][ni][r]);
      }
}

// ===========================================================================
// segment mean over sorted indicator (g bf16 -> hp fp32)
// ===========================================================================
__global__ __launch_bounds__(128) void k_segmean(const short* __restrict__ g,
                                                 const int* __restrict__ idx,
                                                 const int* __restrict__ ind,
                                                 float* __restrict__ hp) {
  __shared__ int sh[2];
  const int s = blockIdx.x;
  if (threadIdx.x == 0) {
    int lo = 0, hi = EE;
    while (lo < hi) { int mid = (lo + hi) >> 1; if (ind[mid] < s) lo = mid + 1; else hi = mid; }
    sh[0] = lo;
    int lo2 = lo, hi2 = EE;
    while (lo2 < hi2) { int mid = (lo2 + hi2) >> 1; if (ind[mid] <= s) lo2 = mid + 1; else hi2 = mid; }
    sh[1] = lo2;
  }
  __syncthreads();
  const int lo = sh[0], hi = sh[1];
  const int d0 = threadIdx.x << 2;
  float a0 = 0.f, a1 = 0.f, a2 = 0.f, a3 = 0.f;
  for (int e = lo; e < hi; ++e) {
    const short4v v = *(const short4v*)(g + (size_t)idx[e] * 512 + d0);
    a0 += b2f(v[0]); a1 += b2f(v[1]); a2 += b2f(v[2]); a3 += b2f(v[3]);
  }
  const float ic = (hi > lo) ? 1.0f / (float)(hi - lo) : 0.0f;
  float4 o = {a0 * ic, a1 * ic, a2 * ic, a3 * ic};
  *(float4*)(hp + (size_t)s * 512 + d0) = o;
}

// ===========================================================================
// BN stats, row-major two-stage
// ===========================================================================
__global__ __launch_bounds__(256) void k_stats1(const float* __restrict__ x,
                                                const float* __restrict__ hp,
                                                float* __restrict__ scr) {
  const int blk = blockIdx.x, tid = threadIdx.x;
  const int c = tid * 2, r0 = blk * 128;
  float sx0 = 0, sx1 = 0, qx0 = 0, qx1 = 0, sh0 = 0, sh1 = 0, qh0 = 0, qh1 = 0;
  for (int r = 0; r < 128; ++r) {
    const size_t off = (size_t)(r0 + r) * 512 + c;
    float2 vx = *(const float2*)(x + off);
    float2 vh = *(const float2*)(hp + off);
    sx0 += vx.x; sx1 += vx.y; qx0 = fmaf(vx.x, vx.x, qx0); qx1 = fmaf(vx.y, vx.y, qx1);
    sh0 += vh.x; sh1 += vh.y; qh0 = fmaf(vh.x, vh.x, qh0); qh1 = fmaf(vh.y, vh.y, qh1);
  }
  float* p = scr + (size_t)blk * 4096;
  p[c] = sx0; p[c + 1] = sx1;
  p[512 + c] = sh0; p[512 + c + 1] = sh1;
  p[2048 + c] = qx0; p[2048 + c + 1] = qx1;
  p[2048 + 512 + c] = qh0; p[2048 + 512 + c + 1] = qh1;
}
__global__ __launch_bounds__(128) void k_stats2(const float* __restrict__ scr,
                                                float* __restrict__ mu, float* __restrict__ inv) {
  const int f = blockIdx.x * 128 + threadIdx.x;
  float s = 0.f, q = 0.f;
  for (int i = 0; i < 32; ++i) {
    s += scr[(size_t)i * 4096 + f];
    q += scr[(size_t)i * 4096 + 2048 + f];
  }
  const float m = s * (1.0f / NNODES);
  mu[f] = m;
  inv[f] = rsqrtf(q * (1.0f / NNODES) - m * m + 1e-5f);
}

// normed (bf16) = BN(concat(x,hp)) * gamma + beta ; grid 4096 x 256
__global__ __launch_bounds__(256) void k_norm(const float* __restrict__ x,
                                              const float* __restrict__ hp,
                                              const float* __restrict__ mu,
                                              const float* __restrict__ inv,
                                              const float* __restrict__ gamma,
                                              const float* __restrict__ beta,
                                              short* __restrict__ nrm) {
  const int gid = blockIdx.x * 256 + threadIdx.x;
  const int n = gid >> 8, f = (gid & 255) << 2;
  float4 v = (f < 512) ? *(const float4*)(x + (size_t)n * 512 + f)
                       : *(const float4*)(hp + (size_t)n * 512 + (f - 512));
  short4v o;
  o[0] = f2bf((v.x - mu[f + 0]) * inv[f + 0] * gamma[f + 0] + beta[f + 0]);
  o[1] = f2bf((v.y - mu[f + 1]) * inv[f + 1] * gamma[f + 1] + beta[f + 1]);
  o[2] = f2bf((v.z - mu[f + 2]) * inv[f + 2] * gamma[f + 2] + beta[f + 2]);
  o[3] = f2bf((v.w - mu[f + 3]) * inv[f + 3] * gamma[f + 3] + beta[f + 3]);
  *(short4v*)(nrm + (size_t)n * 1024 + f) = o;
}

// ===========================================================================
extern "C" void kernel_launch(void* const* d_in, const int* in_sizes, int n_in,
                              void* d_out, int out_size, void* d_ws, size_t ws_size,
                              hipStream_t stream) {
  const float* x     = (const float*)d_in[0];
  const float* Bg    = (const float*)d_in[2];
  const int*   sidx  = (const int*)d_in[3];
  const int*   sind  = (const int*)d_in[4];
  const float* Wq    = (const float*)d_in[6];
  const float* bq    = (const float*)d_in[7];
  const float* Wk    = (const float*)d_in[8];
  const float* bk    = (const float*)d_in[9];
  const float* Wv    = (const float*)d_in[10];
  const float* bv    = (const float*)d_in[11];
  const float* Wo    = (const float*)d_in[12];
  const float* bo    = (const float*)d_in[13];
  const float* Wmp   = (const float*)d_in[14];
  const float* bmp   = (const float*)d_in[15];
  const float* gamma = (const float*)d_in[16];
  const float* beta  = (const float*)d_in[17];
  const float* Wex   = (const float*)d_in[18];
  const float* bex   = (const float*)d_in[19];
  const float* ssp   = (const float*)d_in[20];

  char* W = (char*)d_ws;
  short* x_bf  = (short*)(W + 0);          // 4 MiB
  short* WcatT = (short*)(W + 4194304);    // 2 MiB  [2048][512]
  short* WexT  = (short*)(W + 6291456);    // 1 MiB  [512][1024]
  short* WoT   = (short*)(W + 7340032);    // 512 KiB [512][512]
  float* bcat  = (float*)(W + 7864320);    // 8 KiB
  short* qT    = (short*)(W + 7872512);    // 4 MiB [32][1024][64]
  short* kT    = (short*)(W + 12066816);   // 4 MiB
  short* vT    = (short*)(W + 16261120);   // 4 MiB
  short* g_bf  = (short*)(W + 20455424);   // 4 MiB
  float* hp    = (float*)(W + 24649728);   // 8 MiB
  short* nrm   = (short*)(W + 33038336);   // 8 MiB [4096][1024]
  short* ex_bf = (short*)(W + 41426944);   // 4 MiB
  float* Ksc   = (float*)(W + 45621248);   // 16 MiB [4][1024][1024]
  short* o_bf  = (short*)(W + 62398464);   // 4 MiB
  float* scr   = (float*)(W + 66592768);   // 512 KiB
  float* muv   = (float*)(W + 67117056);   // 4 KiB
  float* invv  = (float*)(W + 67121152);   // 4 KiB

  float* outp = (float*)d_out;
  float* attn = outp + (size_t)BB * LL * HD;

  dim3 t256(256), t32x8(32, 8);

  // casts / packing
  k_cast_x<<<dim3(1024), t256, 0, stream>>>(x, x_bf);
  k_tcast<<<dim3(16, 16), t32x8, 0, stream>>>(Wq,  WcatT,            512, 512);
  k_tcast<<<dim3(16, 16), t32x8, 0, stream>>>(Wk,  WcatT + 512*512,  512, 512);
  k_tcast<<<dim3(16, 16), t32x8, 0, stream>>>(Wv,  WcatT + 1024*512, 512, 512);
  k_tcast<<<dim3(16, 16), t32x8, 0, stream>>>(Wmp, WcatT + 1536*512, 512, 512);
  k_tcast<<<dim3(16, 32), t32x8, 0, stream>>>(Wex, WexT, 1024, 512);
  k_tcast<<<dim3(16, 16), t32x8, 0, stream>>>(Wo,  WoT,  512, 512);
  k_pack_bias<<<dim3(8), t256, 0, stream>>>(bq, bk, bv, bmp, bcat);

  // fused QKV + message passing
  k_gemm_qkvg<<<dim3(16, 32), t256, 0, stream>>>(x_bf, WcatT, bcat, x, qT, kT, vT, g_bf);

  // extractor
  k_segmean<<<dim3(NNODES), dim3(128), 0, stream>>>(g_bf, sidx, sind, hp);
  k_stats1<<<dim3(32), t256, 0, stream>>>(x, hp, scr);
  k_stats2<<<dim3(8), dim3(128), 0, stream>>>(scr, muv, invv);
  k_norm<<<dim3(4096), t256, 0, stream>>>(x, hp, muv, invv, gamma, beta, nrm);
  k_gemm_ex<<<dim3(4, 64), t256, 0, stream>>>(nrm, WexT, bex, ex_bf);

  // structural bias (fused with B_graph + struct_scale)
  k_kstruct<<<dim3(8, 8, 4), t256, 0, stream>>>(ex_bf, Bg, ssp, Ksc);

  // attention
  k_scores<<<dim3(8, 8, 4), t256, 0, stream>>>(qT, kT, Ksc, attn);
  k_softmax<<<dim3(1024, 32), t256, 0, stream>>>(attn);
  k_pv<<<dim3(8, 32), t256, 0, stream>>>(attn, vT, o_bf);

  // output projection
  k_gemm_oproj<<<dim3(4, 64), t256, 0, stream>>>(o_bf, WoT, bo, outp);
}